// Round 17
// baseline (235.789 us; speedup 1.0000x reference)
//
#include <hip/hip_runtime.h>
#include <hip/hip_bf16.h>
#include <math.h>

#define SEQL 2048
#define NB 4
#define DMm 256
#define DIi 512
#define DSs 32
#define NHH 8
#define HDD 64
#define CDD 576
#define ZXD 1096
#define ZXT 2192
#define NPAD 2304
#define NLAY 2
#define QC 64
#define NCH 32
#define RT 8192
#define EPSV 1e-5f

typedef __hip_bfloat16 bf16_t;
using short8 = __attribute__((ext_vector_type(8))) short;
using f32x4  = __attribute__((ext_vector_type(4))) float;

__device__ __forceinline__ float bf16bits2f(short u) {
  union { unsigned int i; float f; } v;
  v.i = ((unsigned int)(unsigned short)u) << 16;
  return v.f;
}

__device__ __forceinline__ int torig(int d, int c, int s) {
  int v = c * QC + s;
  return d ? (SEQL - 1 - v) : v;
}

__device__ __forceinline__ int is_masked(const void* mask, const int* mflag, int r) {
  return (*mflag) ? (int)(((const unsigned char*)mask)[r] != 0)
                  : (int)(((const int*)mask)[r] != 0);
}

// Merged setup + layer-0 LN: blocks 0..1023 convert weights (block 0 also mask-detect);
// blocks 1024..3071 LayerNorm x_in -> h_bf (4 rows each). Independent work.
__global__ __launch_bounds__(256) void setup_kernel(const unsigned char* __restrict__ m,
                             int* __restrict__ flag,
                             const float* __restrict__ in_w, const float* __restrict__ out_w,
                             bf16_t* __restrict__ inw_bf, bf16_t* __restrict__ wcat_bf,
                             const float* __restrict__ x, bf16_t* __restrict__ h,
                             const float* __restrict__ lnw, const float* __restrict__ lnb) {
  if (blockIdx.x >= 1024) {
    int r = (blockIdx.x - 1024) * 4 + (threadIdx.x >> 6), lane = threadIdx.x & 63;
    float4 v = ((const float4*)(x + (size_t)r * DMm))[lane];
    float s = v.x + v.y + v.z + v.w;
    #pragma unroll
    for (int o = 32; o; o >>= 1) s += __shfl_xor(s, o);
    float mu = s * (1.f / DMm);
    float d0 = v.x - mu, d1 = v.y - mu, d2 = v.z - mu, d3 = v.w - mu;
    float q = d0*d0 + d1*d1 + d2*d2 + d3*d3;
    #pragma unroll
    for (int o = 32; o; o >>= 1) q += __shfl_xor(q, o);
    float rstd = rsqrtf(q * (1.f / DMm) + EPSV);
    float4 w  = ((const float4*)lnw)[lane];
    float4 bb = ((const float4*)lnb)[lane];
    union { bf16_t o4[4]; uint2 u; } out;
    out.o4[0] = __float2bfloat16(d0 * rstd * w.x + bb.x);
    out.o4[1] = __float2bfloat16(d1 * rstd * w.y + bb.y);
    out.o4[2] = __float2bfloat16(d2 * rstd * w.z + bb.z);
    out.o4[3] = __float2bfloat16(d3 * rstd * w.w + bb.w);
    ((uint2*)(h + (size_t)r * DMm))[lane] = out.u;
    return;
  }
  if (blockIdx.x == 0) {
    __shared__ int any;
    if (threadIdx.x == 0) any = 0;
    __syncthreads();
    int a = 0;
    for (int i = threadIdx.x; i < RT; i += blockDim.x)
      if ((i & 3) && m[i]) a = 1;
    if (a) atomicOr(&any, 1);
    __syncthreads();
    if (threadIdx.x == 0) *flag = any;
  }
  const int n1 = NLAY * NPAD * DMm;
  const int n2 = NLAY * DMm * 1024;
  for (int idx = blockIdx.x * blockDim.x + threadIdx.x; idx < n1 + n2; idx += 1024 * blockDim.x) {
    if (idx < n1) {
      int l = idx / (NPAD * DMm);
      int rem = idx % (NPAD * DMm);
      int r = rem / DMm, k = rem % DMm;
      inw_bf[idx] = __float2bfloat16(r < ZXT ? in_w[((size_t)l * ZXT + r) * DMm + k] : 0.f);
    } else {
      int j = idx - n1;                            // wcat: [l][d(256)][k(1024)], k = dir*512+e
      int l = j / (DMm * 1024);
      int rem = j % (DMm * 1024);
      int dd = rem >> 10, k = rem & 1023;
      int dir = k >> 9, e = k & 511;
      wcat_bf[j] = __float2bfloat16(out_w[((size_t)((l * 2 + dir) * DMm) + dd) * DIi + e]);
    }
  }
}

// LN: 256 threads = 4 rows/block (one wave per row). (layer-1 only now)
__global__ __launch_bounds__(256) void ln_kernel(const float* __restrict__ x, bf16_t* __restrict__ h,
                          const float* __restrict__ lnw, const float* __restrict__ lnb) {
  int r = blockIdx.x * 4 + (threadIdx.x >> 6), lane = threadIdx.x & 63;
  float4 v = ((const float4*)(x + (size_t)r * DMm))[lane];
  float s = v.x + v.y + v.z + v.w;
  #pragma unroll
  for (int o = 32; o; o >>= 1) s += __shfl_xor(s, o);
  float mu = s * (1.f / DMm);
  float d0 = v.x - mu, d1 = v.y - mu, d2 = v.z - mu, d3 = v.w - mu;
  float q = d0*d0 + d1*d1 + d2*d2 + d3*d3;
  #pragma unroll
  for (int o = 32; o; o >>= 1) q += __shfl_xor(q, o);
  float rstd = rsqrtf(q * (1.f / DMm) + EPSV);
  float4 w  = ((const float4*)lnw)[lane];
  float4 bb = ((const float4*)lnb)[lane];
  union { bf16_t o4[4]; uint2 u; } out;
  out.o4[0] = __float2bfloat16(d0 * rstd * w.x + bb.x);
  out.o4[1] = __float2bfloat16(d1 * rstd * w.y + bb.y);
  out.o4[2] = __float2bfloat16(d2 * rstd * w.z + bb.z);
  out.o4[3] = __float2bfloat16(d3 * rstd * w.w + bb.w);
  ((uint2*)(h + (size_t)r * DMm))[lane] = out.u;
}

// final LN: 4 rows per 256-thread block.
__global__ __launch_bounds__(256) void final_ln(const float* __restrict__ x, const void* __restrict__ mask,
                         const int* __restrict__ mflag,
                         const float* __restrict__ lnw, const float* __restrict__ lnb,
                         float* __restrict__ out) {
  int r = blockIdx.x * 4 + (threadIdx.x >> 6), lane = threadIdx.x & 63;
  float4 v = ((const float4*)(x + (size_t)r * DMm))[lane];
  float s = v.x + v.y + v.z + v.w;
  #pragma unroll
  for (int o = 32; o; o >>= 1) s += __shfl_xor(s, o);
  float mu = s * (1.f / DMm);
  float d0 = v.x - mu, d1 = v.y - mu, d2 = v.z - mu, d3 = v.w - mu;
  float q = d0*d0 + d1*d1 + d2*d2 + d3*d3;
  #pragma unroll
  for (int o = 32; o; o >>= 1) q += __shfl_xor(q, o);
  float rstd = rsqrtf(q * (1.f / DMm) + EPSV);
  float4 w  = ((const float4*)lnw)[lane];
  float4 bb = ((const float4*)lnb)[lane];
  float4 o4;
  if (is_masked(mask, mflag, r)) { o4.x = o4.y = o4.z = o4.w = 0.f; }
  else {
    o4.x = d0 * rstd * w.x + bb.x; o4.y = d1 * rstd * w.y + bb.y;
    o4.z = d2 * rstd * w.z + bb.z; o4.w = d3 * rstd * w.w + bb.w;
  }
  ((float4*)(out + (size_t)r * DMm))[lane] = o4;
}

// In-projection GEMM: 128x128 tile, BK=64, XCD-chunked block swizzle so each XCD
// owns 8 complete row-panels (A fetched once per XCD). Writes bf16 zx + f32 dt.
__global__ __launch_bounds__(256) void gemm_in(const bf16_t* __restrict__ A,
    const bf16_t* __restrict__ Bw, bf16_t* __restrict__ zx, float* __restrict__ dtf) {
  __shared__ __align__(16) bf16_t As[128][72];
  __shared__ __align__(16) bf16_t Bs[128][72];
  // 1152 blocks (18 x 64); bijective chunked remap: XCD q gets rows q*8..q*8+7
  int L = blockIdx.y * 18 + blockIdx.x;
  int qx = L & 7, jx = L >> 3;          // jx in [0,144)
  int Lp = qx * 144 + jx;
  int n0 = (Lp % 18) * 128, m0 = (Lp / 18) * 128;
  int tid = threadIdx.x, lane = tid & 63, wid = tid >> 6;
  int wm = wid >> 1, wn = wid & 1;
  f32x4 acc[4][4] = {};
  int sr = tid >> 1, sh = (tid & 1) * 32;
  for (int k0 = 0; k0 < DMm; k0 += 64) {
    #pragma unroll
    for (int i = 0; i < 4; i++) {
      *(short8*)&As[sr][sh + i * 8] = *(const short8*)(A + (size_t)(m0 + sr) * DMm + k0 + sh + i * 8);
      *(short8*)&Bs[sr][sh + i * 8] = *(const short8*)(Bw + (size_t)(n0 + sr) * DMm + k0 + sh + i * 8);
    }
    __syncthreads();
    #pragma unroll
    for (int kk = 0; kk < 2; kk++) {
      short8 af[4], bf[4];
      #pragma unroll
      for (int mi = 0; mi < 4; mi++)
        af[mi] = *(const short8*)&As[wm * 64 + mi * 16 + (lane & 15)][kk * 32 + (lane >> 4) * 8];
      #pragma unroll
      for (int ni = 0; ni < 4; ni++)
        bf[ni] = *(const short8*)&Bs[wn * 64 + ni * 16 + (lane & 15)][kk * 32 + (lane >> 4) * 8];
      #pragma unroll
      for (int mi = 0; mi < 4; mi++)
        #pragma unroll
        for (int ni = 0; ni < 4; ni++)
          acc[mi][ni] = __builtin_amdgcn_mfma_f32_16x16x32_bf16(af[mi], bf[ni], acc[mi][ni], 0, 0, 0);
    }
    __syncthreads();
  }
  #pragma unroll
  for (int mi = 0; mi < 4; mi++) {
    #pragma unroll
    for (int ni = 0; ni < 4; ni++) {
      int col = n0 + wn * 64 + ni * 16 + (lane & 15);
      if (col < ZXT) {
        #pragma unroll
        for (int j = 0; j < 4; j++) {
          int row = m0 + wm * 64 + mi * 16 + (lane >> 4) * 4 + j;
          float v = acc[mi][ni][j];
          zx[(size_t)row * ZXT + col] = __float2bfloat16(v);
          if (col >= 1088 && col < 1096)
            dtf[(size_t)row * NHH + (col - 1088)] = v;
          else if (col >= 2184)
            dtf[((size_t)RT + row) * NHH + (col - 2184)] = v;
        }
      }
    }
  }
}

// Out-projection GEMM (64x64 tile, BK=64, XCD-chunked swizzle; no fences).
// INIT=1: C = init + (masked?0:acc). INIT=0: masked += into f32 C.
template<int INIT>
__global__ __launch_bounds__(256) void gemm_out(const bf16_t* __restrict__ A, const bf16_t* __restrict__ Bw,
    float* __restrict__ C, const float* __restrict__ init, int ldc,
    const void* __restrict__ mask, const int* __restrict__ mflag) {
  __shared__ __align__(16) bf16_t As[64][72];
  __shared__ __align__(16) bf16_t Bs[64][72];
  const int K = 1024;
  // 512 blocks (4 x 128); chunked remap: XCD q gets Lp in [q*64, q*64+64)
  int L = blockIdx.y * 4 + blockIdx.x;
  int Lp = (L & 7) * 64 + (L >> 3);
  int n0 = (Lp & 3) * 64, m0 = (Lp >> 2) * 64;
  int tid = threadIdx.x, lane = tid & 63, wid = tid >> 6;
  f32x4 acc[4] = {};
  int sr = tid >> 2, sk = (tid & 3) * 16;
  for (int k0 = 0; k0 < K; k0 += 64) {
    *(short8*)&As[sr][sk]     = *(const short8*)(A + (size_t)(m0 + sr) * K + k0 + sk);
    *(short8*)&As[sr][sk + 8] = *(const short8*)(A + (size_t)(m0 + sr) * K + k0 + sk + 8);
    *(short8*)&Bs[sr][sk]     = *(const short8*)(Bw + (size_t)(n0 + sr) * K + k0 + sk);
    *(short8*)&Bs[sr][sk + 8] = *(const short8*)(Bw + (size_t)(n0 + sr) * K + k0 + sk + 8);
    __syncthreads();
    #pragma unroll
    for (int kk = 0; kk < 2; kk++) {
      short8 af = *(const short8*)&As[wid * 16 + (lane & 15)][kk * 32 + (lane >> 4) * 8];
      #pragma unroll
      for (int nt = 0; nt < 4; nt++) {
        short8 bf = *(const short8*)&Bs[nt * 16 + (lane & 15)][kk * 32 + (lane >> 4) * 8];
        acc[nt] = __builtin_amdgcn_mfma_f32_16x16x32_bf16(af, bf, acc[nt], 0, 0, 0);
      }
    }
    __syncthreads();
  }
  #pragma unroll
  for (int nt = 0; nt < 4; nt++) {
    int col = n0 + nt * 16 + (lane & 15);
    #pragma unroll
    for (int j = 0; j < 4; j++) {
      int row = m0 + wid * 16 + (lane >> 4) * 4 + j;
      if (INIT) {
        float base = init[(size_t)row * ldc + col];
        C[(size_t)row * ldc + col] = base + (is_masked(mask, mflag, row) ? 0.f : acc[nt][j]);
      } else {
        if (!is_masked(mask, mflag, row)) C[(size_t)row * ldc + col] += acc[nt][j];
      }
    }
  }
}

// Phase 1 (MFMA) with FUSED conv+silu. Grid (hd, c, b): consecutive blocks share
// the same zx rows (different channel slices) for L2 locality. Conv weights in
// registers; raw staging aliases Ms/Btw. LDS 37.4KB -> 4 blocks/CU.
__global__ __launch_bounds__(256) void chunk_p1(const bf16_t* __restrict__ zx,
    const float* __restrict__ conv_w, const float* __restrict__ conv_b,
    const float* __restrict__ dtf, const float* __restrict__ dt_bias,
    const float* __restrict__ A_log, const float* __restrict__ Dvec,
    bf16_t* __restrict__ ybuf, bf16_t* __restrict__ Sbuf, float* __restrict__ lgbuf,
    float* __restrict__ Pbuf, bf16_t* __restrict__ cbuf, int layer) {
  int hd = blockIdx.x, c = blockIdx.y, b = blockIdx.z;
  int h = hd >> 1, d = hd & 1;
  int tid = threadIdx.x, lane = tid & 63, wid = tid >> 6;
  int rb = b * SEQL;
  __shared__ __align__(16) bf16_t Bs[QC][40];    // B[s][n]
  __shared__ __align__(16) bf16_t Cs[QC][40];    // C[t][n]
  __shared__ __align__(16) bf16_t Xt[QC][72];    // X^T[p][s]
  __shared__ __align__(16) char shraw[17152];    // raw conv in; later Ms+Btw
  bf16_t (*rawX)[64]  = (bf16_t(*)[64])shraw;            //  8576 B (67x64)
  bf16_t (*rawBC)[64] = (bf16_t(*)[64])(shraw + 8576);   //  8576 B
  bf16_t (*Ms)[72]    = (bf16_t(*)[72])shraw;            //  9216 B (aliases raw)
  bf16_t (*Btw)[72]   = (bf16_t(*)[72])(shraw + 9216);   //  4608 B
  __shared__ float lam[QC], dts[QC], wss[QC];

  // conv weights in registers: each thread only ever touches channel (tid&63)
  int chx = tid & 63;
  const float* cwbase = conv_w + (size_t)((layer * 2 + d) * CDD) * 4;
  const float* cbbase = conv_b + (size_t)(layer * 2 + d) * CDD;
  float4 wxv = *(const float4*)(cwbase + (h * HDD + chx) * 4);
  float4 wbv = *(const float4*)(cwbase + (512 + chx) * 4);
  float bx = cbbase[h * HDD + chx];
  float bb = cbbase[512 + chx];

  // P1: raw staging (virtual rows c*64-3 .. c*64+63) + dt-scan
  for (int i = tid; i < 67 * 8; i += 256) {
    int s = i >> 3, p0 = (i & 7) * 8;
    int v = c * QC + s - 3;
    short8 xv = {0,0,0,0,0,0,0,0}, bcv = {0,0,0,0,0,0,0,0};
    if (v >= 0) {
      int t = d ? (SEQL - 1 - v) : v;
      const bf16_t* rowp = zx + (size_t)(rb + t) * ZXT + d * ZXD + DIi;
      xv  = *(const short8*)(rowp + h * HDD + p0);
      bcv = *(const short8*)(rowp + 512 + p0);
    }
    *(short8*)&rawX[s][p0]  = xv;
    *(short8*)&rawBC[s][p0] = bcv;
  }
  if (tid < QC) {  // wave 0: dt, then inclusive scan of log-decay
    int ro = rb + torig(d, c, tid);
    size_t rr = (size_t)d * RT + ro;
    float xv = dtf[rr * NHH + h] + dt_bias[(layer * 2 + d) * NHH + h];
    float dtv = (xv > 20.f) ? xv : log1pf(expf(xv));
    float Ah = -expf(A_log[(layer * 2 + d) * NHH + h]);
    float la = dtv * Ah;
    dts[tid] = dtv;
    #pragma unroll
    for (int o = 1; o < 64; o <<= 1) { float vv = __shfl_up(la, o); if (tid >= o) la += vv; }
    lam[tid] = la;
    Pbuf[rr * NHH + h] = __expf(la);
    float lq = __shfl(la, 63);
    wss[tid] = __expf(lq - la) * dtv;
    if (tid == 63) lgbuf[((b * NHH + h) * 2 + d) * NCH + c] = la;  // log-gamma of chunk
  }
  __syncthreads();

  // P2: conv + silu -> Xt (transposed; 8 s-values batched -> 1 ds_write_b128), Bs, Cs
  {
    int p = chx, sg = tid >> 6;
    #pragma unroll
    for (int half = 0; half < 2; half++) {
      int s0 = sg * 16 + half * 8;
      union { bf16_t h8[8]; short8 v; } ox;
      #pragma unroll
      for (int j = 0; j < 8; j++) {
        int s = s0 + j;
        float a = bx + __bfloat162float(rawX[s + 0][p]) * wxv.x
                     + __bfloat162float(rawX[s + 1][p]) * wxv.y
                     + __bfloat162float(rawX[s + 2][p]) * wxv.z
                     + __bfloat162float(rawX[s + 3][p]) * wxv.w;
        a = a / (1.f + __expf(-a));
        ox.h8[j] = __float2bfloat16(a);
      }
      *(short8*)&Xt[p][s0] = ox.v;
    }
  }
  for (int i = tid; i < QC * HDD; i += 256) {
    int s = i >> 6, q = chx;   // i & 63 == tid & 63 (stride 256)
    float a = bb + __bfloat162float(rawBC[s + 0][q]) * wbv.x
                 + __bfloat162float(rawBC[s + 1][q]) * wbv.y
                 + __bfloat162float(rawBC[s + 2][q]) * wbv.z
                 + __bfloat162float(rawBC[s + 3][q]) * wbv.w;
    a = a / (1.f + __expf(-a));
    bf16_t av = __float2bfloat16(a);
    if (q < DSs) Bs[s][q] = av; else Cs[s][q - DSs] = av;
  }
  __syncthreads();  // protects raw -> Ms alias

  // P3: G = C @ B^T ; M[t][s] = causal exp(lam_t-lam_s)*dt_s*G ; Btw ; cbuf write
  {
    short8 cf = *(const short8*)&Cs[wid * 16 + (lane & 15)][(lane >> 4) * 8];
    int sbase = lane & 15;
    #pragma unroll
    for (int sc = 0; sc < 4; sc++) {
      int s = sc * 16 + sbase;
      if (sc <= wid) {
        short8 bfr = *(const short8*)&Bs[s][(lane >> 4) * 8];
        f32x4 g = {};
        g = __builtin_amdgcn_mfma_f32_16x16x32_bf16(cf, bfr, g, 0, 0, 0);
        float ls = lam[s], dv = dts[s];
        #pragma unroll
        for (int j = 0; j < 4; j++) {
          int t = wid * 16 + (lane >> 4) * 4 + j;
          float m = (s <= t) ? __expf(lam[t] - ls) * dv * g[j] : 0.f;
          Ms[t][s] = __float2bfloat16(m);
        }
      } else {
        #pragma unroll
        for (int j = 0; j < 4; j++) Ms[wid * 16 + (lane >> 4) * 4 + j][s] = __float2bfloat16(0.f);
      }
    }
  }
  for (int i = tid; i < DSs * QC; i += 256) {
    int n = i >> 6, s = i & 63;
    Btw[n][s] = __float2bfloat16(wss[s] * __bfloat162float(Bs[s][n]));
  }
  if (h == 0) {  // compact conv'd C for chunk_p3g
    for (int i = tid; i < QC * DSs; i += 256) {
      int s = i >> 5, n = i & 31;
      cbuf[((size_t)(d * RT + rb + torig(d, c, s))) * DSs + n] = Cs[s][n];
    }
  }
  __syncthreads();

  float Dv = Dvec[(layer * 2 + d) * NHH + h];
  // P4: Y = M @ X + D*x ; S = X^T diag(w) B
  {
    short8 ma0 = *(const short8*)&Ms[wid * 16 + (lane & 15)][(lane >> 4) * 8];
    short8 ma1 = *(const short8*)&Ms[wid * 16 + (lane & 15)][32 + (lane >> 4) * 8];
    int t0 = wid * 16 + (lane >> 4) * 4;
    #pragma unroll
    for (int pt = 0; pt < 4; pt++) {
      short8 xb0 = *(const short8*)&Xt[pt * 16 + (lane & 15)][(lane >> 4) * 8];
      short8 xb1 = *(const short8*)&Xt[pt * 16 + (lane & 15)][32 + (lane >> 4) * 8];
      f32x4 ya = {};
      ya = __builtin_amdgcn_mfma_f32_16x16x32_bf16(ma0, xb0, ya, 0, 0, 0);
      ya = __builtin_amdgcn_mfma_f32_16x16x32_bf16(ma1, xb1, ya, 0, 0, 0);
      int p = pt * 16 + (lane & 15);
      union { uint2 u; short s4[4]; } xr;
      xr.u = *(const uint2*)&Xt[p][t0];   // 4 consecutive t, one 8B read
      #pragma unroll
      for (int j = 0; j < 4; j++) {
        int t = t0 + j;
        float xv = bf16bits2f(xr.s4[j]);
        ybuf[((size_t)(d * RT + rb + torig(d, c, t))) * DIi + h * HDD + p] =
            __float2bfloat16(ya[j] + Dv * xv);
      }
    }
  }
  {
    short8 xa0 = *(const short8*)&Xt[wid * 16 + (lane & 15)][(lane >> 4) * 8];
    short8 xa1 = *(const short8*)&Xt[wid * 16 + (lane & 15)][32 + (lane >> 4) * 8];
    size_t base = ((size_t)((b * NHH + h) * 2 + d) * NCH + c) * 2048;
    #pragma unroll
    for (int nt = 0; nt < 2; nt++) {
      short8 bw0 = *(const short8*)&Btw[nt * 16 + (lane & 15)][(lane >> 4) * 8];
      short8 bw1 = *(const short8*)&Btw[nt * 16 + (lane & 15)][32 + (lane >> 4) * 8];
      f32x4 sa = {};
      sa = __builtin_amdgcn_mfma_f32_16x16x32_bf16(xa0, bw0, sa, 0, 0, 0);
      sa = __builtin_amdgcn_mfma_f32_16x16x32_bf16(xa1, bw1, sa, 0, 0, 0);
      int n = nt * 16 + (lane & 15);
      #pragma unroll
      for (int j = 0; j < 4; j++) {
        int p = wid * 16 + (lane >> 4) * 4 + j;
        Sbuf[base + (size_t)p * DSs + n] = __float2bfloat16(sa[j]);
      }
    }
  }
}

// Phase 2 (parallel): H_c = sum_{c'<c} exp(cum[c-1]-cum[c']) * S_{c'}
__global__ __launch_bounds__(256) void chunk_p2b(const bf16_t* __restrict__ Sbuf,
    const float* __restrict__ lgbuf, bf16_t* __restrict__ Hbuf) {
  int bhd = blockIdx.x, cb = blockIdx.y;
  int tid = threadIdx.x;
  __shared__ float W[NCH][NCH + 1];
  __shared__ float cum[NCH];
  if (tid < NCH) {
    float la = lgbuf[bhd * NCH + tid];
    #pragma unroll
    for (int o = 1; o < NCH; o <<= 1) { float v = __shfl_up(la, o); if (tid >= o) la += v; }
    cum[tid] = la;
  }
  __syncthreads();
  for (int i = tid; i < NCH * NCH; i += 256) {
    int c = i >> 5, cp = i & 31;
    W[c][cp] = (cp < c) ? __expf(cum[c - 1] - cum[cp]) : 0.f;
  }
  __syncthreads();
  int j = cb * 256 + tid;
  const bf16_t* Sb = Sbuf + (size_t)bhd * NCH * 2048;
  bf16_t* Hb = Hbuf + (size_t)bhd * NCH * 2048;
  float H[NCH];
  #pragma unroll
  for (int c = 0; c < NCH; c++) H[c] = 0.f;
  for (int cp = 0; cp < NCH; cp++) {
    float s = __bfloat162float(Sb[(size_t)cp * 2048 + j]);
    #pragma unroll
    for (int c = 0; c < NCH; c++) H[c] += W[c][cp] * s;
  }
  #pragma unroll
  for (int c = 0; c < NCH; c++) Hb[(size_t)c * 2048 + j] = __float2bfloat16(H[c]);
}

// Phase 3 + gate fused: per (half-chunk, d, b) block, 512 threads (8 waves).
// cc swizzled so both half-chunks of a chunk land on the same XCD.
__global__ __launch_bounds__(512) void chunk_p3g(const bf16_t* __restrict__ cbuf,
    const bf16_t* __restrict__ ybuf, const float* __restrict__ Pbuf,
    const bf16_t* __restrict__ Hbuf, const bf16_t* __restrict__ zx,
    const float* __restrict__ gnorm, bf16_t* __restrict__ ycat, int layer) {
  int xb = blockIdx.x;
  int cc = (xb & 7) * 8 + (xb >> 3);   // bijective: pairs (2c,2c+1) share an XCD
  int d = blockIdx.y, b = blockIdx.z;
  int c = cc >> 1, trow0 = (cc & 1) * 32;
  int tid = threadIdx.x, lane = tid & 63, wid = tid >> 6;
  int rb = b * SEQL;
  __shared__ __align__(16) bf16_t Cs[32][40];       // C[trel][n]
  __shared__ __align__(16) bf16_t Hs[NHH][HDD][40]; // H[h][p][n]
  __shared__ __align__(16) bf16_t Ys[32][520];      // y[trel][e]
  __shared__ float Ps[NHH][32];

  for (int i = tid; i < 32 * DSs; i += 512) {
    int s = i >> 5, n = i & 31;
    Cs[s][n] = cbuf[((size_t)(d * RT + rb + torig(d, c, trow0 + s))) * DSs + n];
  }
  for (int i = tid; i < NHH * HDD * DSs; i += 512) {
    int hh = i >> 11, rem = i & 2047;
    Hs[hh][rem >> 5][rem & 31] =
        Hbuf[((size_t)((b * NHH + hh) * 2 + d) * NCH + c) * 2048 + rem];
  }
  if (tid < NHH * 32) {
    int hh = tid >> 5, t = tid & 31;
    Ps[hh][t] = Pbuf[((size_t)(d * RT + rb + torig(d, c, trow0 + t))) * NHH + hh];
  }
  __syncthreads();

  {
    int h = wid;
    #pragma unroll
    for (int tt = 0; tt < 2; tt++) {
      short8 ca = *(const short8*)&Cs[tt * 16 + (lane & 15)][(lane >> 4) * 8];
      #pragma unroll
      for (int pp = 0; pp < 4; pp++) {
        short8 hf = *(const short8*)&Hs[h][pp * 16 + (lane & 15)][(lane >> 4) * 8];
        f32x4 a = {};
        a = __builtin_amdgcn_mfma_f32_16x16x32_bf16(ca, hf, a, 0, 0, 0);
        int p = pp * 16 + (lane & 15);
        #pragma unroll
        for (int j = 0; j < 4; j++) {
          int trel = tt * 16 + (lane >> 4) * 4 + j;
          size_t rr = (size_t)(d * RT + rb + torig(d, c, trow0 + trel));
          float iv = __bfloat162float(ybuf[rr * DIi + h * HDD + p]);
          Ys[trel][h * HDD + p] = __float2bfloat16(iv + Ps[h][trel] * a[j]);
        }
      }
    }
  }
  __syncthreads();

  const float* gw = gnorm + (layer * 2 + d) * DIi;
  #pragma unroll
  for (int rloc = 0; rloc < 4; rloc++) {
    int trel = wid * 4 + rloc;
    int r = rb + torig(d, c, trow0 + trel);
    short8 yv8 = *(const short8*)&Ys[trel][lane * 8];
    short8 zv8 = *(const short8*)(zx + (size_t)r * ZXT + d * ZXD + lane * 8);
    float g[8]; float ss = 0.f;
    #pragma unroll
    for (int j = 0; j < 8; j++) {
      float y = bf16bits2f(yv8[j]);
      float z = bf16bits2f(zv8[j]);
      float v = y * z / (1.f + __expf(-z));
      g[j] = v; ss += v * v;
    }
    #pragma unroll
    for (int o = 32; o; o >>= 1) ss += __shfl_xor(ss, o);
    float sc = rsqrtf(ss * (1.f / DIi) + EPSV);
    union { bf16_t o8[8]; uint4 u; } ov;
    #pragma unroll
    for (int j = 0; j < 8; j++)
      ov.o8[j] = __float2bfloat16(g[j] * sc * gw[lane * 8 + j]);
    *(uint4*)(ycat + (size_t)r * 1024 + d * DIi + lane * 8) = ov.u;
  }
}

extern "C" void kernel_launch(void* const* d_in, const int* in_sizes, int n_in,
                              void* d_out, int out_size, void* d_ws, size_t ws_size,
                              hipStream_t stream) {
  const float* x_in    = (const float*)d_in[0];
  const void*  maskp   = (const void*)d_in[1];
  const float* in_w    = (const float*)d_in[2];
  const float* conv_w  = (const float*)d_in[3];
  const float* conv_b  = (const float*)d_in[4];
  const float* dt_bias = (const float*)d_in[5];
  const float* A_log   = (const float*)d_in[6];
  const float* Dvec    = (const float*)d_in[7];
  const float* gnorm_w = (const float*)d_in[8];
  const float* out_w   = (const float*)d_in[9];
  const float* ln_w    = (const float*)d_in[10];
  const float* ln_b    = (const float*)d_in[11];

  char* ws = (char*)d_ws;
  size_t off = 0;
  auto alloc = [&](size_t bytes) -> void* {
    void* p = ws + off; off += (bytes + 255) & ~(size_t)255; return p;
  };
  float*  x_cur   = (float*)alloc((size_t)RT * DMm * 4);
  bf16_t* h_bf    = (bf16_t*)alloc((size_t)RT * DMm * 2);
  bf16_t* zx      = (bf16_t*)alloc((size_t)RT * ZXT * 2);
  bf16_t* cbuf    = (bf16_t*)alloc((size_t)2 * RT * DSs * 2);
  float*  dtf     = (float*)alloc((size_t)2 * RT * NHH * 4);
  float*  Pbuf    = (float*)alloc((size_t)2 * RT * NHH * 4);
  bf16_t* ybuf    = (bf16_t*)alloc((size_t)2 * RT * DIi * 2);
  bf16_t* ycat    = (bf16_t*)alloc((size_t)RT * 1024 * 2);
  bf16_t* Sbuf    = (bf16_t*)alloc((size_t)64 * NCH * 2048 * 2);
  bf16_t* Hbuf    = (bf16_t*)alloc((size_t)64 * NCH * 2048 * 2);
  float*  lgbuf   = (float*)alloc((size_t)64 * NCH * 4);
  bf16_t* inw_bf  = (bf16_t*)alloc((size_t)NLAY * NPAD * DMm * 2);
  bf16_t* wcat_bf = (bf16_t*)alloc((size_t)NLAY * DMm * 1024 * 2);
  int*    mflag   = (int*)alloc(256);

  setup_kernel<<<3072, 256, 0, stream>>>((const unsigned char*)maskp, mflag,
                                         in_w, out_w, inw_bf, wcat_bf,
                                         x_in, h_bf, ln_w, ln_b);

  for (int layer = 0; layer < NLAY; layer++) {
    if (layer > 0)
      ln_kernel<<<RT / 4, 256, 0, stream>>>(x_cur, h_bf, ln_w, ln_b);
    gemm_in<<<dim3(NPAD / 128, RT / 128), 256, 0, stream>>>(
        h_bf, inw_bf + (size_t)layer * NPAD * DMm, zx, dtf);
    chunk_p1<<<dim3(16, NCH, NB), 256, 0, stream>>>(zx, conv_w, conv_b, dtf, dt_bias,
                                                    A_log, Dvec, ybuf, Sbuf, lgbuf,
                                                    Pbuf, cbuf, layer);
    chunk_p2b<<<dim3(64, 8), 256, 0, stream>>>(Sbuf, lgbuf, Hbuf);
    chunk_p3g<<<dim3(64, 2, NB), 512, 0, stream>>>(cbuf, ybuf, Pbuf, Hbuf, zx,
                                                   gnorm_w, ycat, layer);
    if (layer == 0)
      gemm_out<1><<<dim3(DMm / 64, RT / 64), 256, 0, stream>>>(
          ycat, wcat_bf + (size_t)layer * DMm * 1024, x_cur, x_in,
          DMm, maskp, mflag);
    else
      gemm_out<0><<<dim3(DMm / 64, RT / 64), 256, 0, stream>>>(
          ycat, wcat_bf + (size_t)layer * DMm * 1024, x_cur, nullptr,
          DMm, maskp, mflag);
  }
  final_ln<<<RT / 4, 256, 0, stream>>>(x_cur, maskp, mflag, ln_w, ln_b, (float*)d_out);
}

// Round 18
// 229.687 us; speedup vs baseline: 1.0266x; 1.0266x over previous
//
#include <hip/hip_runtime.h>
#include <hip/hip_bf16.h>
#include <math.h>

#define SEQL 2048
#define NB 4
#define DMm 256
#define DIi 512
#define DSs 32
#define NHH 8
#define HDD 64
#define CDD 576
#define ZXD 1096
#define ZXT 2192
#define NPAD 2304
#define NLAY 2
#define QC 64
#define NCH 32
#define RT 8192
#define EPSV 1e-5f

typedef __hip_bfloat16 bf16_t;
using short8 = __attribute__((ext_vector_type(8))) short;
using f32x4  = __attribute__((ext_vector_type(4))) float;

__device__ __forceinline__ float bf16bits2f(short u) {
  union { unsigned int i; float f; } v;
  v.i = ((unsigned int)(unsigned short)u) << 16;
  return v.f;
}

__device__ __forceinline__ int torig(int d, int c, int s) {
  int v = c * QC + s;
  return d ? (SEQL - 1 - v) : v;
}

__device__ __forceinline__ int is_masked(const void* mask, const int* mflag, int r) {
  return (*mflag) ? (int)(((const unsigned char*)mask)[r] != 0)
                  : (int)(((const int*)mask)[r] != 0);
}

// Merged setup + layer-0 LN: blocks 0..1023 convert weights (block 0 also mask-detect);
// blocks 1024..3071 LayerNorm x_in -> h_bf (4 rows each). Independent work.
__global__ __launch_bounds__(256) void setup_kernel(const unsigned char* __restrict__ m,
                             int* __restrict__ flag,
                             const float* __restrict__ in_w, const float* __restrict__ out_w,
                             bf16_t* __restrict__ inw_bf, bf16_t* __restrict__ wcat_bf,
                             const float* __restrict__ x, bf16_t* __restrict__ h,
                             const float* __restrict__ lnw, const float* __restrict__ lnb) {
  if (blockIdx.x >= 1024) {
    int r = (blockIdx.x - 1024) * 4 + (threadIdx.x >> 6), lane = threadIdx.x & 63;
    float4 v = ((const float4*)(x + (size_t)r * DMm))[lane];
    float s = v.x + v.y + v.z + v.w;
    #pragma unroll
    for (int o = 32; o; o >>= 1) s += __shfl_xor(s, o);
    float mu = s * (1.f / DMm);
    float d0 = v.x - mu, d1 = v.y - mu, d2 = v.z - mu, d3 = v.w - mu;
    float q = d0*d0 + d1*d1 + d2*d2 + d3*d3;
    #pragma unroll
    for (int o = 32; o; o >>= 1) q += __shfl_xor(q, o);
    float rstd = rsqrtf(q * (1.f / DMm) + EPSV);
    float4 w  = ((const float4*)lnw)[lane];
    float4 bb = ((const float4*)lnb)[lane];
    union { bf16_t o4[4]; uint2 u; } out;
    out.o4[0] = __float2bfloat16(d0 * rstd * w.x + bb.x);
    out.o4[1] = __float2bfloat16(d1 * rstd * w.y + bb.y);
    out.o4[2] = __float2bfloat16(d2 * rstd * w.z + bb.z);
    out.o4[3] = __float2bfloat16(d3 * rstd * w.w + bb.w);
    ((uint2*)(h + (size_t)r * DMm))[lane] = out.u;
    return;
  }
  if (blockIdx.x == 0) {
    __shared__ int any;
    if (threadIdx.x == 0) any = 0;
    __syncthreads();
    int a = 0;
    for (int i = threadIdx.x; i < RT; i += blockDim.x)
      if ((i & 3) && m[i]) a = 1;
    if (a) atomicOr(&any, 1);
    __syncthreads();
    if (threadIdx.x == 0) *flag = any;
  }
  const int n1 = NLAY * NPAD * DMm;
  const int n2 = NLAY * DMm * 1024;
  for (int idx = blockIdx.x * blockDim.x + threadIdx.x; idx < n1 + n2; idx += 1024 * blockDim.x) {
    if (idx < n1) {
      int l = idx / (NPAD * DMm);
      int rem = idx % (NPAD * DMm);
      int r = rem / DMm, k = rem % DMm;
      inw_bf[idx] = __float2bfloat16(r < ZXT ? in_w[((size_t)l * ZXT + r) * DMm + k] : 0.f);
    } else {
      int j = idx - n1;                            // wcat: [l][d(256)][k(1024)], k = dir*512+e
      int l = j / (DMm * 1024);
      int rem = j % (DMm * 1024);
      int dd = rem >> 10, k = rem & 1023;
      int dir = k >> 9, e = k & 511;
      wcat_bf[j] = __float2bfloat16(out_w[((size_t)((l * 2 + dir) * DMm) + dd) * DIi + e]);
    }
  }
}

// LN: 256 threads = 4 rows/block (one wave per row). (layer-1 only)
__global__ __launch_bounds__(256) void ln_kernel(const float* __restrict__ x, bf16_t* __restrict__ h,
                          const float* __restrict__ lnw, const float* __restrict__ lnb) {
  int r = blockIdx.x * 4 + (threadIdx.x >> 6), lane = threadIdx.x & 63;
  float4 v = ((const float4*)(x + (size_t)r * DMm))[lane];
  float s = v.x + v.y + v.z + v.w;
  #pragma unroll
  for (int o = 32; o; o >>= 1) s += __shfl_xor(s, o);
  float mu = s * (1.f / DMm);
  float d0 = v.x - mu, d1 = v.y - mu, d2 = v.z - mu, d3 = v.w - mu;
  float q = d0*d0 + d1*d1 + d2*d2 + d3*d3;
  #pragma unroll
  for (int o = 32; o; o >>= 1) q += __shfl_xor(q, o);
  float rstd = rsqrtf(q * (1.f / DMm) + EPSV);
  float4 w  = ((const float4*)lnw)[lane];
  float4 bb = ((const float4*)lnb)[lane];
  union { bf16_t o4[4]; uint2 u; } out;
  out.o4[0] = __float2bfloat16(d0 * rstd * w.x + bb.x);
  out.o4[1] = __float2bfloat16(d1 * rstd * w.y + bb.y);
  out.o4[2] = __float2bfloat16(d2 * rstd * w.z + bb.z);
  out.o4[3] = __float2bfloat16(d3 * rstd * w.w + bb.w);
  ((uint2*)(h + (size_t)r * DMm))[lane] = out.u;
}

// final LN: 4 rows per 256-thread block.
__global__ __launch_bounds__(256) void final_ln(const float* __restrict__ x, const void* __restrict__ mask,
                         const int* __restrict__ mflag,
                         const float* __restrict__ lnw, const float* __restrict__ lnb,
                         float* __restrict__ out) {
  int r = blockIdx.x * 4 + (threadIdx.x >> 6), lane = threadIdx.x & 63;
  float4 v = ((const float4*)(x + (size_t)r * DMm))[lane];
  float s = v.x + v.y + v.z + v.w;
  #pragma unroll
  for (int o = 32; o; o >>= 1) s += __shfl_xor(s, o);
  float mu = s * (1.f / DMm);
  float d0 = v.x - mu, d1 = v.y - mu, d2 = v.z - mu, d3 = v.w - mu;
  float q = d0*d0 + d1*d1 + d2*d2 + d3*d3;
  #pragma unroll
  for (int o = 32; o; o >>= 1) q += __shfl_xor(q, o);
  float rstd = rsqrtf(q * (1.f / DMm) + EPSV);
  float4 w  = ((const float4*)lnw)[lane];
  float4 bb = ((const float4*)lnb)[lane];
  float4 o4;
  if (is_masked(mask, mflag, r)) { o4.x = o4.y = o4.z = o4.w = 0.f; }
  else {
    o4.x = d0 * rstd * w.x + bb.x; o4.y = d1 * rstd * w.y + bb.y;
    o4.z = d2 * rstd * w.z + bb.z; o4.w = d3 * rstd * w.w + bb.w;
  }
  ((float4*)(out + (size_t)r * DMm))[lane] = o4;
}

// In-projection GEMM: 128x128 tile, BK=64, XCD-chunked block swizzle so each XCD
// owns 8 complete row-panels (A fetched once per XCD). Writes bf16 zx + f32 dt.
__global__ __launch_bounds__(256) void gemm_in(const bf16_t* __restrict__ A,
    const bf16_t* __restrict__ Bw, bf16_t* __restrict__ zx, float* __restrict__ dtf) {
  __shared__ __align__(16) bf16_t As[128][72];
  __shared__ __align__(16) bf16_t Bs[128][72];
  // 1152 blocks (18 x 64); bijective chunked remap: XCD q gets rows q*8..q*8+7
  int L = blockIdx.y * 18 + blockIdx.x;
  int qx = L & 7, jx = L >> 3;          // jx in [0,144)
  int Lp = qx * 144 + jx;
  int n0 = (Lp % 18) * 128, m0 = (Lp / 18) * 128;
  int tid = threadIdx.x, lane = tid & 63, wid = tid >> 6;
  int wm = wid >> 1, wn = wid & 1;
  f32x4 acc[4][4] = {};
  int sr = tid >> 1, sh = (tid & 1) * 32;
  for (int k0 = 0; k0 < DMm; k0 += 64) {
    #pragma unroll
    for (int i = 0; i < 4; i++) {
      *(short8*)&As[sr][sh + i * 8] = *(const short8*)(A + (size_t)(m0 + sr) * DMm + k0 + sh + i * 8);
      *(short8*)&Bs[sr][sh + i * 8] = *(const short8*)(Bw + (size_t)(n0 + sr) * DMm + k0 + sh + i * 8);
    }
    __syncthreads();
    #pragma unroll
    for (int kk = 0; kk < 2; kk++) {
      short8 af[4], bf[4];
      #pragma unroll
      for (int mi = 0; mi < 4; mi++)
        af[mi] = *(const short8*)&As[wm * 64 + mi * 16 + (lane & 15)][kk * 32 + (lane >> 4) * 8];
      #pragma unroll
      for (int ni = 0; ni < 4; ni++)
        bf[ni] = *(const short8*)&Bs[wn * 64 + ni * 16 + (lane & 15)][kk * 32 + (lane >> 4) * 8];
      #pragma unroll
      for (int mi = 0; mi < 4; mi++)
        #pragma unroll
        for (int ni = 0; ni < 4; ni++)
          acc[mi][ni] = __builtin_amdgcn_mfma_f32_16x16x32_bf16(af[mi], bf[ni], acc[mi][ni], 0, 0, 0);
    }
    __syncthreads();
  }
  #pragma unroll
  for (int mi = 0; mi < 4; mi++) {
    #pragma unroll
    for (int ni = 0; ni < 4; ni++) {
      int col = n0 + wn * 64 + ni * 16 + (lane & 15);
      if (col < ZXT) {
        #pragma unroll
        for (int j = 0; j < 4; j++) {
          int row = m0 + wm * 64 + mi * 16 + (lane >> 4) * 4 + j;
          float v = acc[mi][ni][j];
          zx[(size_t)row * ZXT + col] = __float2bfloat16(v);
          if (col >= 1088 && col < 1096)
            dtf[(size_t)row * NHH + (col - 1088)] = v;
          else if (col >= 2184)
            dtf[((size_t)RT + row) * NHH + (col - 2184)] = v;
        }
      }
    }
  }
}

// Out-projection GEMM (64x64 tile, BK=64, XCD-chunked swizzle; no fences).
// INIT=1: C = init + (masked?0:acc). INIT=0: masked += into f32 C.
template<int INIT>
__global__ __launch_bounds__(256) void gemm_out(const bf16_t* __restrict__ A, const bf16_t* __restrict__ Bw,
    float* __restrict__ C, const float* __restrict__ init, int ldc,
    const void* __restrict__ mask, const int* __restrict__ mflag) {
  __shared__ __align__(16) bf16_t As[64][72];
  __shared__ __align__(16) bf16_t Bs[64][72];
  const int K = 1024;
  // 512 blocks (4 x 128); chunked remap: XCD q gets Lp in [q*64, q*64+64)
  int L = blockIdx.y * 4 + blockIdx.x;
  int Lp = (L & 7) * 64 + (L >> 3);
  int n0 = (Lp & 3) * 64, m0 = (Lp >> 2) * 64;
  int tid = threadIdx.x, lane = tid & 63, wid = tid >> 6;
  f32x4 acc[4] = {};
  int sr = tid >> 2, sk = (tid & 3) * 16;
  for (int k0 = 0; k0 < K; k0 += 64) {
    *(short8*)&As[sr][sk]     = *(const short8*)(A + (size_t)(m0 + sr) * K + k0 + sk);
    *(short8*)&As[sr][sk + 8] = *(const short8*)(A + (size_t)(m0 + sr) * K + k0 + sk + 8);
    *(short8*)&Bs[sr][sk]     = *(const short8*)(Bw + (size_t)(n0 + sr) * K + k0 + sk);
    *(short8*)&Bs[sr][sk + 8] = *(const short8*)(Bw + (size_t)(n0 + sr) * K + k0 + sk + 8);
    __syncthreads();
    #pragma unroll
    for (int kk = 0; kk < 2; kk++) {
      short8 af = *(const short8*)&As[wid * 16 + (lane & 15)][kk * 32 + (lane >> 4) * 8];
      #pragma unroll
      for (int nt = 0; nt < 4; nt++) {
        short8 bf = *(const short8*)&Bs[nt * 16 + (lane & 15)][kk * 32 + (lane >> 4) * 8];
        acc[nt] = __builtin_amdgcn_mfma_f32_16x16x32_bf16(af, bf, acc[nt], 0, 0, 0);
      }
    }
    __syncthreads();
  }
  #pragma unroll
  for (int nt = 0; nt < 4; nt++) {
    int col = n0 + nt * 16 + (lane & 15);
    #pragma unroll
    for (int j = 0; j < 4; j++) {
      int row = m0 + wid * 16 + (lane >> 4) * 4 + j;
      if (INIT) {
        float base = init[(size_t)row * ldc + col];
        C[(size_t)row * ldc + col] = base + (is_masked(mask, mflag, row) ? 0.f : acc[nt][j]);
      } else {
        if (!is_masked(mask, mflag, row)) C[(size_t)row * ldc + col] += acc[nt][j];
      }
    }
  }
}

// Phase 1 (MFMA) with FUSED conv+silu: grid (c, hd, b). Conv weights in registers;
// raw staging aliases Ms/Btw. LDS 37.4KB -> 4 blocks/CU.
__global__ __launch_bounds__(256) void chunk_p1(const bf16_t* __restrict__ zx,
    const float* __restrict__ conv_w, const float* __restrict__ conv_b,
    const float* __restrict__ dtf, const float* __restrict__ dt_bias,
    const float* __restrict__ A_log, const float* __restrict__ Dvec,
    bf16_t* __restrict__ ybuf, bf16_t* __restrict__ Sbuf, float* __restrict__ lgbuf,
    float* __restrict__ Pbuf, bf16_t* __restrict__ cbuf, int layer) {
  int c = blockIdx.x, hd = blockIdx.y, b = blockIdx.z;
  int h = hd >> 1, d = hd & 1;
  int tid = threadIdx.x, lane = tid & 63, wid = tid >> 6;
  int rb = b * SEQL;
  __shared__ __align__(16) bf16_t Bs[QC][40];    // B[s][n]
  __shared__ __align__(16) bf16_t Cs[QC][40];    // C[t][n]
  __shared__ __align__(16) bf16_t Xt[QC][72];    // X^T[p][s]
  __shared__ __align__(16) char shraw[17152];    // raw conv in; later Ms+Btw
  bf16_t (*rawX)[64]  = (bf16_t(*)[64])shraw;            //  8576 B (67x64)
  bf16_t (*rawBC)[64] = (bf16_t(*)[64])(shraw + 8576);   //  8576 B
  bf16_t (*Ms)[72]    = (bf16_t(*)[72])shraw;            //  9216 B (aliases raw)
  bf16_t (*Btw)[72]   = (bf16_t(*)[72])(shraw + 9216);   //  4608 B
  __shared__ float lam[QC], dts[QC], wss[QC];

  // conv weights in registers: each thread only ever touches channel (tid&63)
  int chx = tid & 63;
  const float* cwbase = conv_w + (size_t)((layer * 2 + d) * CDD) * 4;
  const float* cbbase = conv_b + (size_t)(layer * 2 + d) * CDD;
  float4 wxv = *(const float4*)(cwbase + (h * HDD + chx) * 4);
  float4 wbv = *(const float4*)(cwbase + (512 + chx) * 4);
  float bx = cbbase[h * HDD + chx];
  float bb = cbbase[512 + chx];

  // P1: raw staging (virtual rows c*64-3 .. c*64+63) + dt-scan
  for (int i = tid; i < 67 * 8; i += 256) {
    int s = i >> 3, p0 = (i & 7) * 8;
    int v = c * QC + s - 3;
    short8 xv = {0,0,0,0,0,0,0,0}, bcv = {0,0,0,0,0,0,0,0};
    if (v >= 0) {
      int t = d ? (SEQL - 1 - v) : v;
      const bf16_t* rowp = zx + (size_t)(rb + t) * ZXT + d * ZXD + DIi;
      xv  = *(const short8*)(rowp + h * HDD + p0);
      bcv = *(const short8*)(rowp + 512 + p0);
    }
    *(short8*)&rawX[s][p0]  = xv;
    *(short8*)&rawBC[s][p0] = bcv;
  }
  if (tid < QC) {  // wave 0: dt, then inclusive scan of log-decay
    int ro = rb + torig(d, c, tid);
    size_t rr = (size_t)d * RT + ro;
    float xv = dtf[rr * NHH + h] + dt_bias[(layer * 2 + d) * NHH + h];
    float dtv = (xv > 20.f) ? xv : log1pf(expf(xv));
    float Ah = -expf(A_log[(layer * 2 + d) * NHH + h]);
    float la = dtv * Ah;
    dts[tid] = dtv;
    #pragma unroll
    for (int o = 1; o < 64; o <<= 1) { float vv = __shfl_up(la, o); if (tid >= o) la += vv; }
    lam[tid] = la;
    Pbuf[rr * NHH + h] = __expf(la);
    float lq = __shfl(la, 63);
    wss[tid] = __expf(lq - la) * dtv;
    if (tid == 63) lgbuf[((b * NHH + h) * 2 + d) * NCH + c] = la;  // log-gamma of chunk
  }
  __syncthreads();

  // P2: conv + silu -> Xt (transposed; 8 s-values batched -> 1 ds_write_b128), Bs, Cs
  {
    int p = chx, sg = tid >> 6;
    #pragma unroll
    for (int half = 0; half < 2; half++) {
      int s0 = sg * 16 + half * 8;
      union { bf16_t h8[8]; short8 v; } ox;
      #pragma unroll
      for (int j = 0; j < 8; j++) {
        int s = s0 + j;
        float a = bx + __bfloat162float(rawX[s + 0][p]) * wxv.x
                     + __bfloat162float(rawX[s + 1][p]) * wxv.y
                     + __bfloat162float(rawX[s + 2][p]) * wxv.z
                     + __bfloat162float(rawX[s + 3][p]) * wxv.w;
        a = a / (1.f + __expf(-a));
        ox.h8[j] = __float2bfloat16(a);
      }
      *(short8*)&Xt[p][s0] = ox.v;
    }
  }
  for (int i = tid; i < QC * HDD; i += 256) {
    int s = i >> 6, q = chx;   // i & 63 == tid & 63 (stride 256)
    float a = bb + __bfloat162float(rawBC[s + 0][q]) * wbv.x
                 + __bfloat162float(rawBC[s + 1][q]) * wbv.y
                 + __bfloat162float(rawBC[s + 2][q]) * wbv.z
                 + __bfloat162float(rawBC[s + 3][q]) * wbv.w;
    a = a / (1.f + __expf(-a));
    bf16_t av = __float2bfloat16(a);
    if (q < DSs) Bs[s][q] = av; else Cs[s][q - DSs] = av;
  }
  __syncthreads();  // protects raw -> Ms alias

  // P3: G = C @ B^T ; M[t][s] = causal exp(lam_t-lam_s)*dt_s*G ; Btw ; cbuf write
  {
    short8 cf = *(const short8*)&Cs[wid * 16 + (lane & 15)][(lane >> 4) * 8];
    int sbase = lane & 15;
    #pragma unroll
    for (int sc = 0; sc < 4; sc++) {
      int s = sc * 16 + sbase;
      if (sc <= wid) {
        short8 bfr = *(const short8*)&Bs[s][(lane >> 4) * 8];
        f32x4 g = {};
        g = __builtin_amdgcn_mfma_f32_16x16x32_bf16(cf, bfr, g, 0, 0, 0);
        float ls = lam[s], dv = dts[s];
        #pragma unroll
        for (int j = 0; j < 4; j++) {
          int t = wid * 16 + (lane >> 4) * 4 + j;
          float m = (s <= t) ? __expf(lam[t] - ls) * dv * g[j] : 0.f;
          Ms[t][s] = __float2bfloat16(m);
        }
      } else {
        #pragma unroll
        for (int j = 0; j < 4; j++) Ms[wid * 16 + (lane >> 4) * 4 + j][s] = __float2bfloat16(0.f);
      }
    }
  }
  for (int i = tid; i < DSs * QC; i += 256) {
    int n = i >> 6, s = i & 63;
    Btw[n][s] = __float2bfloat16(wss[s] * __bfloat162float(Bs[s][n]));
  }
  if (h == 0) {  // compact conv'd C for chunk_p3g
    for (int i = tid; i < QC * DSs; i += 256) {
      int s = i >> 5, n = i & 31;
      cbuf[((size_t)(d * RT + rb + torig(d, c, s))) * DSs + n] = Cs[s][n];
    }
  }
  __syncthreads();

  float Dv = Dvec[(layer * 2 + d) * NHH + h];
  // P4: Y = M @ X + D*x ; S = X^T diag(w) B
  {
    short8 ma0 = *(const short8*)&Ms[wid * 16 + (lane & 15)][(lane >> 4) * 8];
    short8 ma1 = *(const short8*)&Ms[wid * 16 + (lane & 15)][32 + (lane >> 4) * 8];
    int t0 = wid * 16 + (lane >> 4) * 4;
    #pragma unroll
    for (int pt = 0; pt < 4; pt++) {
      short8 xb0 = *(const short8*)&Xt[pt * 16 + (lane & 15)][(lane >> 4) * 8];
      short8 xb1 = *(const short8*)&Xt[pt * 16 + (lane & 15)][32 + (lane >> 4) * 8];
      f32x4 ya = {};
      ya = __builtin_amdgcn_mfma_f32_16x16x32_bf16(ma0, xb0, ya, 0, 0, 0);
      ya = __builtin_amdgcn_mfma_f32_16x16x32_bf16(ma1, xb1, ya, 0, 0, 0);
      int p = pt * 16 + (lane & 15);
      union { uint2 u; short s4[4]; } xr;
      xr.u = *(const uint2*)&Xt[p][t0];   // 4 consecutive t, one 8B read
      #pragma unroll
      for (int j = 0; j < 4; j++) {
        int t = t0 + j;
        float xv = bf16bits2f(xr.s4[j]);
        ybuf[((size_t)(d * RT + rb + torig(d, c, t))) * DIi + h * HDD + p] =
            __float2bfloat16(ya[j] + Dv * xv);
      }
    }
  }
  {
    short8 xa0 = *(const short8*)&Xt[wid * 16 + (lane & 15)][(lane >> 4) * 8];
    short8 xa1 = *(const short8*)&Xt[wid * 16 + (lane & 15)][32 + (lane >> 4) * 8];
    size_t base = ((size_t)((b * NHH + h) * 2 + d) * NCH + c) * 2048;
    #pragma unroll
    for (int nt = 0; nt < 2; nt++) {
      short8 bw0 = *(const short8*)&Btw[nt * 16 + (lane & 15)][(lane >> 4) * 8];
      short8 bw1 = *(const short8*)&Btw[nt * 16 + (lane & 15)][32 + (lane >> 4) * 8];
      f32x4 sa = {};
      sa = __builtin_amdgcn_mfma_f32_16x16x32_bf16(xa0, bw0, sa, 0, 0, 0);
      sa = __builtin_amdgcn_mfma_f32_16x16x32_bf16(xa1, bw1, sa, 0, 0, 0);
      int n = nt * 16 + (lane & 15);
      #pragma unroll
      for (int j = 0; j < 4; j++) {
        int p = wid * 16 + (lane >> 4) * 4 + j;
        Sbuf[base + (size_t)p * DSs + n] = __float2bfloat16(sa[j]);
      }
    }
  }
}

// Phase 2 (parallel): H_c = sum_{c'<c} exp(cum[c-1]-cum[c']) * S_{c'}
__global__ __launch_bounds__(256) void chunk_p2b(const bf16_t* __restrict__ Sbuf,
    const float* __restrict__ lgbuf, bf16_t* __restrict__ Hbuf) {
  int bhd = blockIdx.x, cb = blockIdx.y;
  int tid = threadIdx.x;
  __shared__ float W[NCH][NCH + 1];
  __shared__ float cum[NCH];
  if (tid < NCH) {
    float la = lgbuf[bhd * NCH + tid];
    #pragma unroll
    for (int o = 1; o < NCH; o <<= 1) { float v = __shfl_up(la, o); if (tid >= o) la += v; }
    cum[tid] = la;
  }
  __syncthreads();
  for (int i = tid; i < NCH * NCH; i += 256) {
    int c = i >> 5, cp = i & 31;
    W[c][cp] = (cp < c) ? __expf(cum[c - 1] - cum[cp]) : 0.f;
  }
  __syncthreads();
  int j = cb * 256 + tid;
  const bf16_t* Sb = Sbuf + (size_t)bhd * NCH * 2048;
  bf16_t* Hb = Hbuf + (size_t)bhd * NCH * 2048;
  float H[NCH];
  #pragma unroll
  for (int c = 0; c < NCH; c++) H[c] = 0.f;
  for (int cp = 0; cp < NCH; cp++) {
    float s = __bfloat162float(Sb[(size_t)cp * 2048 + j]);
    #pragma unroll
    for (int c = 0; c < NCH; c++) H[c] += W[c][cp] * s;
  }
  #pragma unroll
  for (int c = 0; c < NCH; c++) Hb[(size_t)c * 2048 + j] = __float2bfloat16(H[c]);
}

// Phase 3 + gate fused: per (half-chunk, d, b) block, 512 threads (8 waves).
__global__ __launch_bounds__(512) void chunk_p3g(const bf16_t* __restrict__ cbuf,
    const bf16_t* __restrict__ ybuf, const float* __restrict__ Pbuf,
    const bf16_t* __restrict__ Hbuf, const bf16_t* __restrict__ zx,
    const float* __restrict__ gnorm, bf16_t* __restrict__ ycat, int layer) {
  int cc = blockIdx.x, d = blockIdx.y, b = blockIdx.z;
  int c = cc >> 1, trow0 = (cc & 1) * 32;
  int tid = threadIdx.x, lane = tid & 63, wid = tid >> 6;
  int rb = b * SEQL;
  __shared__ __align__(16) bf16_t Cs[32][40];       // C[trel][n]
  __shared__ __align__(16) bf16_t Hs[NHH][HDD][40]; // H[h][p][n]
  __shared__ __align__(16) bf16_t Ys[32][520];      // y[trel][e]
  __shared__ float Ps[NHH][32];

  for (int i = tid; i < 32 * DSs; i += 512) {
    int s = i >> 5, n = i & 31;
    Cs[s][n] = cbuf[((size_t)(d * RT + rb + torig(d, c, trow0 + s))) * DSs + n];
  }
  for (int i = tid; i < NHH * HDD * DSs; i += 512) {
    int hh = i >> 11, rem = i & 2047;
    Hs[hh][rem >> 5][rem & 31] =
        Hbuf[((size_t)((b * NHH + hh) * 2 + d) * NCH + c) * 2048 + rem];
  }
  if (tid < NHH * 32) {
    int hh = tid >> 5, t = tid & 31;
    Ps[hh][t] = Pbuf[((size_t)(d * RT + rb + torig(d, c, trow0 + t))) * NHH + hh];
  }
  __syncthreads();

  {
    int h = wid;
    #pragma unroll
    for (int tt = 0; tt < 2; tt++) {
      short8 ca = *(const short8*)&Cs[tt * 16 + (lane & 15)][(lane >> 4) * 8];
      #pragma unroll
      for (int pp = 0; pp < 4; pp++) {
        short8 hf = *(const short8*)&Hs[h][pp * 16 + (lane & 15)][(lane >> 4) * 8];
        f32x4 a = {};
        a = __builtin_amdgcn_mfma_f32_16x16x32_bf16(ca, hf, a, 0, 0, 0);
        int p = pp * 16 + (lane & 15);
        #pragma unroll
        for (int j = 0; j < 4; j++) {
          int trel = tt * 16 + (lane >> 4) * 4 + j;
          size_t rr = (size_t)(d * RT + rb + torig(d, c, trow0 + trel));
          float iv = __bfloat162float(ybuf[rr * DIi + h * HDD + p]);
          Ys[trel][h * HDD + p] = __float2bfloat16(iv + Ps[h][trel] * a[j]);
        }
      }
    }
  }
  __syncthreads();

  const float* gw = gnorm + (layer * 2 + d) * DIi;
  #pragma unroll
  for (int rloc = 0; rloc < 4; rloc++) {
    int trel = wid * 4 + rloc;
    int r = rb + torig(d, c, trow0 + trel);
    short8 yv8 = *(const short8*)&Ys[trel][lane * 8];
    short8 zv8 = *(const short8*)(zx + (size_t)r * ZXT + d * ZXD + lane * 8);
    float g[8]; float ss = 0.f;
    #pragma unroll
    for (int j = 0; j < 8; j++) {
      float y = bf16bits2f(yv8[j]);
      float z = bf16bits2f(zv8[j]);
      float v = y * z / (1.f + __expf(-z));
      g[j] = v; ss += v * v;
    }
    #pragma unroll
    for (int o = 32; o; o >>= 1) ss += __shfl_xor(ss, o);
    float sc = rsqrtf(ss * (1.f / DIi) + EPSV);
    union { bf16_t o8[8]; uint4 u; } ov;
    #pragma unroll
    for (int j = 0; j < 8; j++)
      ov.o8[j] = __float2bfloat16(g[j] * sc * gw[lane * 8 + j]);
    *(uint4*)(ycat + (size_t)r * 1024 + d * DIi + lane * 8) = ov.u;
  }
}

extern "C" void kernel_launch(void* const* d_in, const int* in_sizes, int n_in,
                              void* d_out, int out_size, void* d_ws, size_t ws_size,
                              hipStream_t stream) {
  const float* x_in    = (const float*)d_in[0];
  const void*  maskp   = (const void*)d_in[1];
  const float* in_w    = (const float*)d_in[2];
  const float* conv_w  = (const float*)d_in[3];
  const float* conv_b  = (const float*)d_in[4];
  const float* dt_bias = (const float*)d_in[5];
  const float* A_log   = (const float*)d_in[6];
  const float* Dvec    = (const float*)d_in[7];
  const float* gnorm_w = (const float*)d_in[8];
  const float* out_w   = (const float*)d_in[9];
  const float* ln_w    = (const float*)d_in[10];
  const float* ln_b    = (const float*)d_in[11];

  char* ws = (char*)d_ws;
  size_t off = 0;
  auto alloc = [&](size_t bytes) -> void* {
    void* p = ws + off; off += (bytes + 255) & ~(size_t)255; return p;
  };
  float*  x_cur   = (float*)alloc((size_t)RT * DMm * 4);
  bf16_t* h_bf    = (bf16_t*)alloc((size_t)RT * DMm * 2);
  bf16_t* zx      = (bf16_t*)alloc((size_t)RT * ZXT * 2);
  bf16_t* cbuf    = (bf16_t*)alloc((size_t)2 * RT * DSs * 2);
  float*  dtf     = (float*)alloc((size_t)2 * RT * NHH * 4);
  float*  Pbuf    = (float*)alloc((size_t)2 * RT * NHH * 4);
  bf16_t* ybuf    = (bf16_t*)alloc((size_t)2 * RT * DIi * 2);
  bf16_t* ycat    = (bf16_t*)alloc((size_t)RT * 1024 * 2);
  bf16_t* Sbuf    = (bf16_t*)alloc((size_t)64 * NCH * 2048 * 2);
  bf16_t* Hbuf    = (bf16_t*)alloc((size_t)64 * NCH * 2048 * 2);
  float*  lgbuf   = (float*)alloc((size_t)64 * NCH * 4);
  bf16_t* inw_bf  = (bf16_t*)alloc((size_t)NLAY * NPAD * DMm * 2);
  bf16_t* wcat_bf = (bf16_t*)alloc((size_t)NLAY * DMm * 1024 * 2);
  int*    mflag   = (int*)alloc(256);

  setup_kernel<<<3072, 256, 0, stream>>>((const unsigned char*)maskp, mflag,
                                         in_w, out_w, inw_bf, wcat_bf,
                                         x_in, h_bf, ln_w, ln_b);

  for (int layer = 0; layer < NLAY; layer++) {
    if (layer > 0)
      ln_kernel<<<RT / 4, 256, 0, stream>>>(x_cur, h_bf, ln_w, ln_b);
    gemm_in<<<dim3(NPAD / 128, RT / 128), 256, 0, stream>>>(
        h_bf, inw_bf + (size_t)layer * NPAD * DMm, zx, dtf);
    chunk_p1<<<dim3(NCH, 16, NB), 256, 0, stream>>>(zx, conv_w, conv_b, dtf, dt_bias,
                                                    A_log, Dvec, ybuf, Sbuf, lgbuf,
                                                    Pbuf, cbuf, layer);
    chunk_p2b<<<dim3(64, 8), 256, 0, stream>>>(Sbuf, lgbuf, Hbuf);
    chunk_p3g<<<dim3(64, 2, NB), 512, 0, stream>>>(cbuf, ybuf, Pbuf, Hbuf, zx,
                                                   gnorm_w, ycat, layer);
    if (layer == 0)
      gemm_out<1><<<dim3(DMm / 64, RT / 64), 256, 0, stream>>>(
          ycat, wcat_bf + (size_t)layer * DMm * 1024, x_cur, x_in,
          DMm, maskp, mflag);
    else
      gemm_out<0><<<dim3(DMm / 64, RT / 64), 256, 0, stream>>>(
          ycat, wcat_bf + (size_t)layer * DMm * 1024, x_cur, nullptr,
          DMm, maskp, mflag);
  }
  final_ln<<<RT / 4, 256, 0, stream>>>(x_cur, maskp, mflag, ln_w, ln_b, (float*)d_out);
}